// Round 4
// baseline (79.181 us; speedup 1.0000x reference)
//
#include <hip/hip_runtime.h>
#include <math.h>

#define NBOX  25200   // boxes per batch: 3*(6400+1600+400)
#define BS    32
#define TPB   256
#define BPT   2       // boxes per thread
#define BPB   (TPB * BPT)                 // 512
#define NBLK  ((NBOX + BPB - 1) / BPB)    // 50 blocks per batch
#define NBLKS (NBLK * BS)                 // 1600 total blocks

typedef float f4 __attribute__((ext_vector_type(4), aligned(4)));
typedef float f2 __attribute__((ext_vector_type(2), aligned(4)));

// fast sigmoid: v_exp_f32-based __expf + fast rcp; ~1e-6 rel err vs 1.7e-2 threshold
__device__ __forceinline__ float sigm(float x) {
    return __fdividef(1.0f, 1.0f + __expf(-x));
}

// pointer + decode metadata for global box index i of batch b
// anchor select via ?: chains (no runtime-indexed arrays -> no scratch)
__device__ __forceinline__ const float* box_ptr(const float* __restrict__ p0,
                                                const float* __restrict__ p1,
                                                const float* __restrict__ p2,
                                                int b, int i,
                                                float& fgx, float& fgy,
                                                float& stride, float& aw, float& ah) {
    if (i < 19200) {
        const int j = i;                       // (a*80+y)*80+x
        const int a = j / 6400;
        const int cell = j - a * 6400;
        const int gy = cell / 80;
        const int gx = cell - gy * 80;
        fgx = (float)gx; fgy = (float)gy;
        stride = 8.0f;
        aw = (a == 0) ? 10.f : ((a == 1) ? 16.f : 33.f);
        ah = (a == 0) ? 13.f : ((a == 1) ? 30.f : 23.f);
        return p0 + ((size_t)b * 19200 + j) * 85;
    } else if (i < 24000) {
        const int j = i - 19200;
        const int a = j / 1600;
        const int cell = j - a * 1600;
        const int gy = cell / 40;
        const int gx = cell - gy * 40;
        fgx = (float)gx; fgy = (float)gy;
        stride = 16.0f;
        aw = (a == 0) ? 30.f : ((a == 1) ? 62.f : 59.f);
        ah = (a == 0) ? 61.f : ((a == 1) ? 45.f : 119.f);
        return p1 + ((size_t)b * 4800 + j) * 85;
    } else {
        const int j = i - 24000;
        const int a = j / 400;
        const int cell = j - a * 400;
        const int gy = cell / 20;
        const int gx = cell - gy * 20;
        fgx = (float)gx; fgy = (float)gy;
        stride = 32.0f;
        aw = (a == 0) ? 116.f : ((a == 1) ? 156.f : 373.f);
        ah = (a == 0) ? 90.f : ((a == 1) ? 198.f : 326.f);
        return p2 + ((size_t)b * 1200 + j) * 85;
    }
}

__global__ __launch_bounds__(TPB) void yolo_fused_kernel(const float* __restrict__ p0,
                                                         const float* __restrict__ p1,
                                                         const float* __restrict__ p2,
                                                         const float* __restrict__ gt,
                                                         const float* __restrict__ thrp,
                                                         float* __restrict__ ws,
                                                         unsigned int* __restrict__ ctr,
                                                         float* __restrict__ out) {
    const int b = blockIdx.y;

    const float gx1 = gt[b * 4 + 0];
    const float gy1 = gt[b * 4 + 1];
    const float gx2 = gt[b * 4 + 2];
    const float gy2 = gt[b * 4 + 3];
    const float thr = thrp[0];
    const float area_g = (gx2 - gx1) * (gy2 - gy1);

    // phase 1: pointers + metadata
    const float* q[BPT];
    float fgx[BPT], fgy[BPT], strd[BPT], aw[BPT], ah[BPT];
    bool act[BPT];
    #pragma unroll
    for (int u = 0; u < BPT; ++u) {
        const int i = blockIdx.x * BPB + u * TPB + threadIdx.x;
        act[u] = (i < NBOX);
        const int ic = act[u] ? i : 0;
        q[u] = box_ptr(p0, p1, p2, b, ic, fgx[u], fgy[u], strd[u], aw[u], ah[u]);
    }

    // phase 2: issue all loads (dwordx4 + dwordx2 per box)
    f4 v0[BPT];
    f2 v1[BPT];
    #pragma unroll
    for (int u = 0; u < BPT; ++u) {
        v0[u] = *(const f4*)(q[u]);
        v1[u] = *(const f2*)(q[u] + 4);
    }

    // phase 3: decode + IoU + masked score
    float val = 0.0f;
    #pragma unroll
    for (int u = 0; u < BPT; ++u) {
        const float sx = sigm(v0[u].x), sy = sigm(v0[u].y);
        const float sw = sigm(v0[u].z), sh = sigm(v0[u].w);
        const float sobj = sigm(v1[u].x), scls = sigm(v1[u].y);

        const float cx = (sx * 2.0f - 0.5f + fgx[u]) * strd[u];
        const float cy = (sy * 2.0f - 0.5f + fgy[u]) * strd[u];
        const float tw = sw * 2.0f, th = sh * 2.0f;
        const float w = tw * tw * aw[u];
        const float h = th * th * ah[u];
        const float x1 = cx - w * 0.5f, x2 = cx + w * 0.5f;
        const float y1 = cy - h * 0.5f, y2 = cy + h * 0.5f;

        float iw = fminf(x2, gx2) - fmaxf(x1, gx1);
        float ih = fminf(y2, gy2) - fmaxf(y1, gy1);
        iw = fmaxf(iw, 0.0f);
        ih = fmaxf(ih, 0.0f);
        const float inter = iw * ih;
        const float area_b = (x2 - x1) * (y2 - y1);
        const float iou = __fdividef(inter, area_b + area_g - inter);

        const float s = sobj * scls;
        val = fmaxf(val, (act[u] && iou >= thr) ? s : 0.0f);
    }

    // block max reduce: 4 waves of 64
    #pragma unroll
    for (int off = 32; off > 0; off >>= 1)
        val = fmaxf(val, __shfl_down(val, off, 64));

    __shared__ float smax[4];
    __shared__ bool is_last;
    const int lane = threadIdx.x & 63;
    const int wid = threadIdx.x >> 6;
    if (lane == 0) smax[wid] = val;
    __syncthreads();
    if (threadIdx.x == 0) {
        // unconditional write of all NBLKS slots every call -> poison-safe
        ws[b * NBLK + blockIdx.x] =
            fmaxf(fmaxf(smax[0], smax[1]), fmaxf(smax[2], smax[3]));
        __threadfence();                       // release: slot visible before arrival
        const unsigned int old = atomicAdd(ctr, 1u);
        is_last = (old == NBLKS - 1);
    }
    __syncthreads();

    if (!is_last) return;

    // last-arriving block: all 1600 slots are visible (fence + atomic order)
    __threadfence();                           // acquire side
    const int t = threadIdx.x;
    const int batch = t >> 3;    // 0..31 (8 lanes per batch; groups within one wave)
    const int sub = t & 7;

    float m = 0.0f;
    for (int k = sub; k < NBLK; k += 8)
        m = fmaxf(m, ws[batch * NBLK + k]);

    m = fmaxf(m, __shfl_xor(m, 1, 64));
    m = fmaxf(m, __shfl_xor(m, 2, 64));
    m = fmaxf(m, __shfl_xor(m, 4, 64));

    __shared__ float sm[BS];
    if (sub == 0) { sm[batch] = m; out[1 + batch] = m; }
    __syncthreads();
    if (t == 0) {
        float s = 0.0f;
        #pragma unroll
        for (int b2 = 0; b2 < BS; ++b2) s += sm[b2];
        out[0] = s * (1.0f / 32.0f);   // fixed-order sum -> deterministic
    }
}

extern "C" void kernel_launch(void* const* d_in, const int* in_sizes, int n_in,
                              void* d_out, int out_size, void* d_ws, size_t ws_size,
                              hipStream_t stream) {
    const float* p0  = (const float*)d_in[0];
    const float* p1  = (const float*)d_in[1];
    const float* p2  = (const float*)d_in[2];
    const float* gt  = (const float*)d_in[3];
    const float* thr = (const float*)d_in[4];
    float* out = (float*)d_out;
    float* ws  = (float*)d_ws;                          // NBLKS floats = 6.4 KB
    unsigned int* ctr = (unsigned int*)(ws + NBLKS);    // 4 B arrival counter

    hipMemsetAsync(ctr, 0, sizeof(unsigned int), stream);  // graph-legal memset node

    dim3 grid(NBLK, BS);
    yolo_fused_kernel<<<grid, TPB, 0, stream>>>(p0, p1, p2, gt, thr, ws, ctr, out);
}

// Round 5
// 41.515 us; speedup vs baseline: 1.9073x; 1.9073x over previous
//
#include <hip/hip_runtime.h>
#include <math.h>

#define NBOX  25200   // boxes per batch: 3*(6400+1600+400)
#define BS    32
#define TPB   256
#define BPT   2       // boxes per thread
#define BPB   (TPB * BPT)                 // 512
#define NBLK  ((NBOX + BPB - 1) / BPB)    // 50 blocks per batch
#define NBLKS (NBLK * BS)                 // 1600 total blocks

typedef float f4 __attribute__((ext_vector_type(4), aligned(4)));
typedef float f2 __attribute__((ext_vector_type(2), aligned(4)));

// fast sigmoid: v_exp_f32-based __expf + fast rcp; ~1e-6 rel err vs 1.7e-2 threshold
__device__ __forceinline__ float sigm(float x) {
    return __fdividef(1.0f, 1.0f + __expf(-x));
}

// pointer + decode metadata for global box index i of batch b
// anchor select via ?: chains (no runtime-indexed arrays -> no scratch)
__device__ __forceinline__ const float* box_ptr(const float* __restrict__ p0,
                                                const float* __restrict__ p1,
                                                const float* __restrict__ p2,
                                                int b, int i,
                                                float& fgx, float& fgy,
                                                float& stride, float& aw, float& ah) {
    if (i < 19200) {
        const int j = i;                       // (a*80+y)*80+x
        const int a = j / 6400;
        const int cell = j - a * 6400;
        const int gy = cell / 80;
        const int gx = cell - gy * 80;
        fgx = (float)gx; fgy = (float)gy;
        stride = 8.0f;
        aw = (a == 0) ? 10.f : ((a == 1) ? 16.f : 33.f);
        ah = (a == 0) ? 13.f : ((a == 1) ? 30.f : 23.f);
        return p0 + ((size_t)b * 19200 + j) * 85;
    } else if (i < 24000) {
        const int j = i - 19200;
        const int a = j / 1600;
        const int cell = j - a * 1600;
        const int gy = cell / 40;
        const int gx = cell - gy * 40;
        fgx = (float)gx; fgy = (float)gy;
        stride = 16.0f;
        aw = (a == 0) ? 30.f : ((a == 1) ? 62.f : 59.f);
        ah = (a == 0) ? 61.f : ((a == 1) ? 45.f : 119.f);
        return p1 + ((size_t)b * 4800 + j) * 85;
    } else {
        const int j = i - 24000;
        const int a = j / 400;
        const int cell = j - a * 400;
        const int gy = cell / 20;
        const int gx = cell - gy * 20;
        fgx = (float)gx; fgy = (float)gy;
        stride = 32.0f;
        aw = (a == 0) ? 116.f : ((a == 1) ? 156.f : 373.f);
        ah = (a == 0) ? 90.f : ((a == 1) ? 198.f : 326.f);
        return p2 + ((size_t)b * 1200 + j) * 85;
    }
}

__global__ __launch_bounds__(TPB) void yolo_fused_kernel(const float* __restrict__ p0,
                                                         const float* __restrict__ p1,
                                                         const float* __restrict__ p2,
                                                         const float* __restrict__ gt,
                                                         const float* __restrict__ thrp,
                                                         float* __restrict__ ws,
                                                         unsigned int* __restrict__ ctr,
                                                         float* __restrict__ out) {
    const int b = blockIdx.y;

    const float gx1 = gt[b * 4 + 0];
    const float gy1 = gt[b * 4 + 1];
    const float gx2 = gt[b * 4 + 2];
    const float gy2 = gt[b * 4 + 3];
    const float thr = thrp[0];
    const float area_g = (gx2 - gx1) * (gy2 - gy1);

    // phase 1: pointers + metadata
    const float* q[BPT];
    float fgx[BPT], fgy[BPT], strd[BPT], aw[BPT], ah[BPT];
    bool act[BPT];
    #pragma unroll
    for (int u = 0; u < BPT; ++u) {
        const int i = blockIdx.x * BPB + u * TPB + threadIdx.x;
        act[u] = (i < NBOX);
        const int ic = act[u] ? i : 0;
        q[u] = box_ptr(p0, p1, p2, b, ic, fgx[u], fgy[u], strd[u], aw[u], ah[u]);
    }

    // phase 2: issue all loads (dwordx4 + dwordx2 per box)
    f4 v0[BPT];
    f2 v1[BPT];
    #pragma unroll
    for (int u = 0; u < BPT; ++u) {
        v0[u] = *(const f4*)(q[u]);
        v1[u] = *(const f2*)(q[u] + 4);
    }

    // phase 3: decode + IoU + masked score
    float val = 0.0f;
    #pragma unroll
    for (int u = 0; u < BPT; ++u) {
        const float sx = sigm(v0[u].x), sy = sigm(v0[u].y);
        const float sw = sigm(v0[u].z), sh = sigm(v0[u].w);
        const float sobj = sigm(v1[u].x), scls = sigm(v1[u].y);

        const float cx = (sx * 2.0f - 0.5f + fgx[u]) * strd[u];
        const float cy = (sy * 2.0f - 0.5f + fgy[u]) * strd[u];
        const float tw = sw * 2.0f, th = sh * 2.0f;
        const float w = tw * tw * aw[u];
        const float h = th * th * ah[u];
        const float x1 = cx - w * 0.5f, x2 = cx + w * 0.5f;
        const float y1 = cy - h * 0.5f, y2 = cy + h * 0.5f;

        float iw = fminf(x2, gx2) - fmaxf(x1, gx1);
        float ih = fminf(y2, gy2) - fmaxf(y1, gy1);
        iw = fmaxf(iw, 0.0f);
        ih = fmaxf(ih, 0.0f);
        const float inter = iw * ih;
        const float area_b = (x2 - x1) * (y2 - y1);
        const float iou = __fdividef(inter, area_b + area_g - inter);

        const float s = sobj * scls;
        val = fmaxf(val, (act[u] && iou >= thr) ? s : 0.0f);
    }

    // block max reduce: 4 waves of 64
    #pragma unroll
    for (int off = 32; off > 0; off >>= 1)
        val = fmaxf(val, __shfl_down(val, off, 64));

    __shared__ float smax[4];
    __shared__ bool is_last;
    const int lane = threadIdx.x & 63;
    const int wid = threadIdx.x >> 6;
    if (lane == 0) smax[wid] = val;
    __syncthreads();
    if (threadIdx.x == 0) {
        const float bm = fmaxf(fmaxf(smax[0], smax[1]), fmaxf(smax[2], smax[3]));
        // sc0/sc1 store: bypasses L1/L2, lands at the coherent (memory-side L3)
        // point -> per-word cross-XCD visibility WITHOUT any L2 writeback.
        __hip_atomic_store(&ws[b * NBLK + blockIdx.x], bm,
                           __ATOMIC_RELAXED, __HIP_MEMORY_SCOPE_AGENT);
        // order: slot store must complete at the coherence point before the
        // arrival counter increments (LLVM's release recipe minus the wbl2,
        // which is unnecessary because the store itself bypassed L2).
        __builtin_amdgcn_sched_barrier(0);
        asm volatile("s_waitcnt vmcnt(0)" ::: "memory");
        __builtin_amdgcn_sched_barrier(0);
        const unsigned int old = __hip_atomic_fetch_add(ctr, 1u,
                                   __ATOMIC_RELAXED, __HIP_MEMORY_SCOPE_AGENT);
        is_last = (old == NBLKS - 1);
    }
    __syncthreads();

    if (!is_last) return;

    // last-arriving block: all slots are at the coherence point; read them with
    // cache-bypassing (sc0/sc1) loads -> no buffer_inv needed.
    const int t = threadIdx.x;
    const int batch = t >> 3;    // 0..31 (8 lanes per batch; groups within one wave)
    const int sub = t & 7;

    float m = 0.0f;
    for (int k = sub; k < NBLK; k += 8)
        m = fmaxf(m, __hip_atomic_load(&ws[batch * NBLK + k],
                                       __ATOMIC_RELAXED, __HIP_MEMORY_SCOPE_AGENT));

    m = fmaxf(m, __shfl_xor(m, 1, 64));
    m = fmaxf(m, __shfl_xor(m, 2, 64));
    m = fmaxf(m, __shfl_xor(m, 4, 64));

    __shared__ float sm[BS];
    if (sub == 0) { sm[batch] = m; out[1 + batch] = m; }
    __syncthreads();
    if (t == 0) {
        float s = 0.0f;
        #pragma unroll
        for (int b2 = 0; b2 < BS; ++b2) s += sm[b2];
        out[0] = s * (1.0f / 32.0f);   // fixed-order sum -> deterministic
    }
}

extern "C" void kernel_launch(void* const* d_in, const int* in_sizes, int n_in,
                              void* d_out, int out_size, void* d_ws, size_t ws_size,
                              hipStream_t stream) {
    const float* p0  = (const float*)d_in[0];
    const float* p1  = (const float*)d_in[1];
    const float* p2  = (const float*)d_in[2];
    const float* gt  = (const float*)d_in[3];
    const float* thr = (const float*)d_in[4];
    float* out = (float*)d_out;
    float* ws  = (float*)d_ws;                          // NBLKS floats = 6.4 KB
    unsigned int* ctr = (unsigned int*)(ws + NBLKS);    // 4 B arrival counter

    hipMemsetAsync(ctr, 0, sizeof(unsigned int), stream);  // graph-legal memset node

    dim3 grid(NBLK, BS);
    yolo_fused_kernel<<<grid, TPB, 0, stream>>>(p0, p1, p2, gt, thr, ws, ctr, out);
}

// Round 6
// 27.471 us; speedup vs baseline: 2.8823x; 1.5112x over previous
//
#include <hip/hip_runtime.h>
#include <math.h>

#define NBOX 25200   // boxes per batch: 3*(6400+1600+400)
#define BS   32
#define TPB  256
#define BPT  4       // boxes per thread (8 vmem loads in flight per thread)
#define BPB  (TPB * BPT)                 // 1024
#define NBLK ((NBOX + BPB - 1) / BPB)    // 25 blocks per batch

typedef float f4 __attribute__((ext_vector_type(4), aligned(4)));
typedef float f2 __attribute__((ext_vector_type(2), aligned(4)));

// fast sigmoid: v_exp_f32-based __expf + fast rcp; ~1e-6 rel err vs 1.7e-2 threshold
__device__ __forceinline__ float sigm(float x) {
    return __fdividef(1.0f, 1.0f + __expf(-x));
}

// pointer + decode metadata for global box index i of batch b
// anchor select via ?: chains (no runtime-indexed arrays -> no scratch)
__device__ __forceinline__ const float* box_ptr(const float* __restrict__ p0,
                                                const float* __restrict__ p1,
                                                const float* __restrict__ p2,
                                                int b, int i,
                                                float& fgx, float& fgy,
                                                float& stride, float& aw, float& ah) {
    if (i < 19200) {
        const int j = i;                       // (a*80+y)*80+x
        const int a = j / 6400;
        const int cell = j - a * 6400;
        const int gy = cell / 80;
        const int gx = cell - gy * 80;
        fgx = (float)gx; fgy = (float)gy;
        stride = 8.0f;
        aw = (a == 0) ? 10.f : ((a == 1) ? 16.f : 33.f);
        ah = (a == 0) ? 13.f : ((a == 1) ? 30.f : 23.f);
        return p0 + ((size_t)b * 19200 + j) * 85;
    } else if (i < 24000) {
        const int j = i - 19200;
        const int a = j / 1600;
        const int cell = j - a * 1600;
        const int gy = cell / 40;
        const int gx = cell - gy * 40;
        fgx = (float)gx; fgy = (float)gy;
        stride = 16.0f;
        aw = (a == 0) ? 30.f : ((a == 1) ? 62.f : 59.f);
        ah = (a == 0) ? 61.f : ((a == 1) ? 45.f : 119.f);
        return p1 + ((size_t)b * 4800 + j) * 85;
    } else {
        const int j = i - 24000;
        const int a = j / 400;
        const int cell = j - a * 400;
        const int gy = cell / 20;
        const int gx = cell - gy * 20;
        fgx = (float)gx; fgy = (float)gy;
        stride = 32.0f;
        aw = (a == 0) ? 116.f : ((a == 1) ? 156.f : 373.f);
        ah = (a == 0) ? 90.f : ((a == 1) ? 198.f : 326.f);
        return p2 + ((size_t)b * 1200 + j) * 85;
    }
}

__global__ __launch_bounds__(TPB) void yolo_max_kernel(const float* __restrict__ p0,
                                                       const float* __restrict__ p1,
                                                       const float* __restrict__ p2,
                                                       const float* __restrict__ gt,
                                                       const float* __restrict__ thrp,
                                                       float* __restrict__ ws) {
    const int b = blockIdx.y;

    const float gx1 = gt[b * 4 + 0];
    const float gy1 = gt[b * 4 + 1];
    const float gx2 = gt[b * 4 + 2];
    const float gy2 = gt[b * 4 + 3];
    const float thr = thrp[0];
    const float area_g = (gx2 - gx1) * (gy2 - gy1);

    // phase 1: pointers + metadata for all boxes
    const float* q[BPT];
    float fgx[BPT], fgy[BPT], strd[BPT], aw[BPT], ah[BPT];
    bool act[BPT];
    #pragma unroll
    for (int u = 0; u < BPT; ++u) {
        const int i = blockIdx.x * BPB + u * TPB + threadIdx.x;
        act[u] = (i < NBOX);
        const int ic = act[u] ? i : 0;
        q[u] = box_ptr(p0, p1, p2, b, ic, fgx[u], fgy[u], strd[u], aw[u], ah[u]);
    }

    // phase 2: issue ALL loads back-to-back (8 vmem instrs in flight/thread)
    f4 v0[BPT];
    f2 v1[BPT];
    #pragma unroll
    for (int u = 0; u < BPT; ++u) {
        v0[u] = *(const f4*)(q[u]);
        v1[u] = *(const f2*)(q[u] + 4);
    }

    // phase 3: decode + IoU + masked score
    float val = 0.0f;
    #pragma unroll
    for (int u = 0; u < BPT; ++u) {
        const float sx = sigm(v0[u].x), sy = sigm(v0[u].y);
        const float sw = sigm(v0[u].z), sh = sigm(v0[u].w);
        const float sobj = sigm(v1[u].x), scls = sigm(v1[u].y);

        const float cx = (sx * 2.0f - 0.5f + fgx[u]) * strd[u];
        const float cy = (sy * 2.0f - 0.5f + fgy[u]) * strd[u];
        const float tw = sw * 2.0f, th = sh * 2.0f;
        const float w = tw * tw * aw[u];
        const float h = th * th * ah[u];
        const float x1 = cx - w * 0.5f, x2 = cx + w * 0.5f;
        const float y1 = cy - h * 0.5f, y2 = cy + h * 0.5f;

        float iw = fminf(x2, gx2) - fmaxf(x1, gx1);
        float ih = fminf(y2, gy2) - fmaxf(y1, gy1);
        iw = fmaxf(iw, 0.0f);
        ih = fmaxf(ih, 0.0f);
        const float inter = iw * ih;
        const float area_b = (x2 - x1) * (y2 - y1);
        const float iou = __fdividef(inter, area_b + area_g - inter);

        const float s = sobj * scls;
        val = fmaxf(val, (act[u] && iou >= thr) ? s : 0.0f);
    }

    // block max reduce: 4 waves of 64
    #pragma unroll
    for (int off = 32; off > 0; off >>= 1)
        val = fmaxf(val, __shfl_down(val, off, 64));

    __shared__ float smax[4];
    const int lane = threadIdx.x & 63;
    const int wid = threadIdx.x >> 6;
    if (lane == 0) smax[wid] = val;
    __syncthreads();
    if (threadIdx.x == 0) {
        // unconditional write of all NBLK*BS slots every call -> no init needed
        ws[b * NBLK + blockIdx.x] =
            fmaxf(fmaxf(smax[0], smax[1]), fmaxf(smax[2], smax[3]));
    }
}

__global__ void finalize_kernel(const float* __restrict__ ws, float* __restrict__ out) {
    // 256 threads: 8 lanes per batch, 32 batches
    const int t = threadIdx.x;
    const int batch = t >> 3;    // 0..31
    const int sub = t & 7;

    float m = 0.0f;
    for (int k = sub; k < NBLK; k += 8)
        m = fmaxf(m, ws[batch * NBLK + k]);

    // reduce within the 8-lane group (same wave)
    m = fmaxf(m, __shfl_xor(m, 1, 64));
    m = fmaxf(m, __shfl_xor(m, 2, 64));
    m = fmaxf(m, __shfl_xor(m, 4, 64));

    __shared__ float sm[BS];
    if (sub == 0) { sm[batch] = m; out[1 + batch] = m; }
    __syncthreads();
    if (t == 0) {
        float s = 0.0f;
        #pragma unroll
        for (int b2 = 0; b2 < BS; ++b2) s += sm[b2];
        out[0] = s * (1.0f / 32.0f);   // fixed-order sum -> deterministic
    }
}

extern "C" void kernel_launch(void* const* d_in, const int* in_sizes, int n_in,
                              void* d_out, int out_size, void* d_ws, size_t ws_size,
                              hipStream_t stream) {
    const float* p0  = (const float*)d_in[0];
    const float* p1  = (const float*)d_in[1];
    const float* p2  = (const float*)d_in[2];
    const float* gt  = (const float*)d_in[3];
    const float* thr = (const float*)d_in[4];
    float* out = (float*)d_out;
    float* ws  = (float*)d_ws;   // NBLK*BS floats = 3.2 KB

    dim3 grid(NBLK, BS);
    yolo_max_kernel<<<grid, TPB, 0, stream>>>(p0, p1, p2, gt, thr, ws);
    finalize_kernel<<<1, TPB, 0, stream>>>(ws, out);
}

// Round 7
// 25.498 us; speedup vs baseline: 3.1054x; 1.0774x over previous
//
#include <hip/hip_runtime.h>
#include <math.h>

#define NBOX 25200   // boxes per batch: 3*(6400+1600+400)
#define BS   32
#define TPB  256
#define BPT  2       // boxes per thread (empirically best: R3 = 26.0 us; BPT=4 was 27.5)
#define BPB  (TPB * BPT)                 // 512
#define NBLK ((NBOX + BPB - 1) / BPB)    // 50 blocks per batch

typedef float f4 __attribute__((ext_vector_type(4), aligned(4)));
typedef float f2 __attribute__((ext_vector_type(2), aligned(4)));

// fast sigmoid: v_exp_f32-based __expf + fast rcp; ~1e-6 rel err vs 1.7e-2 threshold
__device__ __forceinline__ float sigm(float x) {
    return __fdividef(1.0f, 1.0f + __expf(-x));
}

// pointer + decode metadata for global box index i of batch b
// anchor select via ?: chains (no runtime-indexed arrays -> no scratch)
__device__ __forceinline__ const float* box_ptr(const float* __restrict__ p0,
                                                const float* __restrict__ p1,
                                                const float* __restrict__ p2,
                                                int b, int i,
                                                float& fgx, float& fgy,
                                                float& stride, float& aw, float& ah) {
    if (i < 19200) {
        const int j = i;                       // (a*80+y)*80+x
        const int a = j / 6400;
        const int cell = j - a * 6400;
        const int gy = cell / 80;
        const int gx = cell - gy * 80;
        fgx = (float)gx; fgy = (float)gy;
        stride = 8.0f;
        aw = (a == 0) ? 10.f : ((a == 1) ? 16.f : 33.f);
        ah = (a == 0) ? 13.f : ((a == 1) ? 30.f : 23.f);
        return p0 + ((size_t)b * 19200 + j) * 85;
    } else if (i < 24000) {
        const int j = i - 19200;
        const int a = j / 1600;
        const int cell = j - a * 1600;
        const int gy = cell / 40;
        const int gx = cell - gy * 40;
        fgx = (float)gx; fgy = (float)gy;
        stride = 16.0f;
        aw = (a == 0) ? 30.f : ((a == 1) ? 62.f : 59.f);
        ah = (a == 0) ? 61.f : ((a == 1) ? 45.f : 119.f);
        return p1 + ((size_t)b * 4800 + j) * 85;
    } else {
        const int j = i - 24000;
        const int a = j / 400;
        const int cell = j - a * 400;
        const int gy = cell / 20;
        const int gx = cell - gy * 20;
        fgx = (float)gx; fgy = (float)gy;
        stride = 32.0f;
        aw = (a == 0) ? 116.f : ((a == 1) ? 156.f : 373.f);
        ah = (a == 0) ? 90.f : ((a == 1) ? 198.f : 326.f);
        return p2 + ((size_t)b * 1200 + j) * 85;
    }
}

__global__ __launch_bounds__(TPB) void yolo_max_kernel(const float* __restrict__ p0,
                                                       const float* __restrict__ p1,
                                                       const float* __restrict__ p2,
                                                       const float* __restrict__ gt,
                                                       const float* __restrict__ thrp,
                                                       float* __restrict__ ws) {
    const int b = blockIdx.y;

    const float gx1 = gt[b * 4 + 0];
    const float gy1 = gt[b * 4 + 1];
    const float gx2 = gt[b * 4 + 2];
    const float gy2 = gt[b * 4 + 3];
    const float thr = thrp[0];
    const float area_g = (gx2 - gx1) * (gy2 - gy1);

    // phase 1: pointers + metadata
    const float* q[BPT];
    float fgx[BPT], fgy[BPT], strd[BPT], aw[BPT], ah[BPT];
    bool act[BPT];
    #pragma unroll
    for (int u = 0; u < BPT; ++u) {
        const int i = blockIdx.x * BPB + u * TPB + threadIdx.x;
        act[u] = (i < NBOX);
        const int ic = act[u] ? i : 0;
        q[u] = box_ptr(p0, p1, p2, b, ic, fgx[u], fgy[u], strd[u], aw[u], ah[u]);
    }

    // phase 2: issue all loads (dwordx4 + dwordx2 per box)
    f4 v0[BPT];
    f2 v1[BPT];
    #pragma unroll
    for (int u = 0; u < BPT; ++u) {
        v0[u] = *(const f4*)(q[u]);
        v1[u] = *(const f2*)(q[u] + 4);
    }

    // phase 3: decode + IoU + masked score
    float val = 0.0f;
    #pragma unroll
    for (int u = 0; u < BPT; ++u) {
        const float sx = sigm(v0[u].x), sy = sigm(v0[u].y);
        const float sw = sigm(v0[u].z), sh = sigm(v0[u].w);
        const float sobj = sigm(v1[u].x), scls = sigm(v1[u].y);

        const float cx = (sx * 2.0f - 0.5f + fgx[u]) * strd[u];
        const float cy = (sy * 2.0f - 0.5f + fgy[u]) * strd[u];
        const float tw = sw * 2.0f, th = sh * 2.0f;
        const float w = tw * tw * aw[u];
        const float h = th * th * ah[u];
        const float x1 = cx - w * 0.5f, x2 = cx + w * 0.5f;
        const float y1 = cy - h * 0.5f, y2 = cy + h * 0.5f;

        float iw = fminf(x2, gx2) - fmaxf(x1, gx1);
        float ih = fminf(y2, gy2) - fmaxf(y1, gy1);
        iw = fmaxf(iw, 0.0f);
        ih = fmaxf(ih, 0.0f);
        const float inter = iw * ih;
        const float area_b = (x2 - x1) * (y2 - y1);
        const float iou = __fdividef(inter, area_b + area_g - inter);

        const float s = sobj * scls;
        val = fmaxf(val, (act[u] && iou >= thr) ? s : 0.0f);
    }

    // block max reduce: 4 waves of 64
    #pragma unroll
    for (int off = 32; off > 0; off >>= 1)
        val = fmaxf(val, __shfl_down(val, off, 64));

    __shared__ float smax[4];
    const int lane = threadIdx.x & 63;
    const int wid = threadIdx.x >> 6;
    if (lane == 0) smax[wid] = val;
    __syncthreads();
    if (threadIdx.x == 0) {
        // unconditional write of all NBLK*BS slots every call -> no init needed
        ws[b * NBLK + blockIdx.x] =
            fmaxf(fmaxf(smax[0], smax[1]), fmaxf(smax[2], smax[3]));
    }
}

__global__ void finalize_kernel(const float* __restrict__ ws, float* __restrict__ out) {
    // 256 threads: 8 lanes per batch, 32 batches
    const int t = threadIdx.x;
    const int batch = t >> 3;    // 0..31
    const int sub = t & 7;

    float m = 0.0f;
    for (int k = sub; k < NBLK; k += 8)
        m = fmaxf(m, ws[batch * NBLK + k]);

    // reduce within the 8-lane group (same wave)
    m = fmaxf(m, __shfl_xor(m, 1, 64));
    m = fmaxf(m, __shfl_xor(m, 2, 64));
    m = fmaxf(m, __shfl_xor(m, 4, 64));

    __shared__ float sm[BS];
    if (sub == 0) { sm[batch] = m; out[1 + batch] = m; }
    __syncthreads();
    if (t == 0) {
        float s = 0.0f;
        #pragma unroll
        for (int b2 = 0; b2 < BS; ++b2) s += sm[b2];
        out[0] = s * (1.0f / 32.0f);   // fixed-order sum -> deterministic
    }
}

extern "C" void kernel_launch(void* const* d_in, const int* in_sizes, int n_in,
                              void* d_out, int out_size, void* d_ws, size_t ws_size,
                              hipStream_t stream) {
    const float* p0  = (const float*)d_in[0];
    const float* p1  = (const float*)d_in[1];
    const float* p2  = (const float*)d_in[2];
    const float* gt  = (const float*)d_in[3];
    const float* thr = (const float*)d_in[4];
    float* out = (float*)d_out;
    float* ws  = (float*)d_ws;   // NBLK*BS floats = 6.4 KB

    dim3 grid(NBLK, BS);
    yolo_max_kernel<<<grid, TPB, 0, stream>>>(p0, p1, p2, gt, thr, ws);
    finalize_kernel<<<1, TPB, 0, stream>>>(ws, out);
}